// Round 1
// baseline (220.783 us; speedup 1.0000x reference)
//
#include <hip/hip_runtime.h>

// Problem: out[b, x, y] = sum_k inputs[b,k] * W[y*82+x, k] + bias[y*82+x]
//   B=8192, F=64, P=5494 (NX=82, NY=67), out flat: b*5494 + x*67 + y
// Strategy: permute+convert W to bf16 once (Wp[c]=W[p(c)]), convert inputs to
// bf16, then a plain row-major GEMM [8192,64]x[64,5504] with MFMA bf16.
// Output writes are contiguous; operands are L2-resident so fragments are
// loaded directly from global (no LDS staging needed at K=64).

typedef __bf16 bf16x8 __attribute__((ext_vector_type(8)));
typedef float f32x4 __attribute__((ext_vector_type(4)));

#define B_DIM 8192
#define F_DIM 64
#define P_DIM 5494
#define PP_DIM 5504   // P padded to multiple of 128
#define NY_C 67

// round-to-nearest-even fp32 -> bf16
__device__ __forceinline__ unsigned short f2bf(float f) {
  unsigned int u = __float_as_uint(f);
  unsigned int r = u + 0x7fffu + ((u >> 16) & 1u);
  return (unsigned short)(r >> 16);
}

// Convert inputs [8192*64] fp32 -> bf16. 4 elems/thread. 131072 threads.
__global__ void cvt_a_kernel(const float* __restrict__ A,
                             unsigned short* __restrict__ Abf) {
  int i = (blockIdx.x * 256 + threadIdx.x) * 4;
  float4 v = *(const float4*)(A + i);
  *(ushort4*)(Abf + i) = make_ushort4(f2bf(v.x), f2bf(v.y), f2bf(v.z), f2bf(v.w));
}

// Permute + convert W: Wp[c][k] = bf16(W[p(c)][k]), c = x*67+y, p = y*82+x.
// Pads c in [5494,5504) with zeros. Also builds permuted bias bp[c].
// 16 threads per c-row (4 floats each). 5504*16 = 88064 threads = 344 blocks.
__global__ void cvt_w_kernel(const float* __restrict__ W,
                             const float* __restrict__ bias,
                             unsigned short* __restrict__ Wp,
                             float* __restrict__ bp) {
  int t = blockIdx.x * 256 + threadIdx.x;
  int c = t >> 4;
  int kq = (t & 15) * 4;
  int x = c / NY_C;
  int y = c - x * NY_C;
  if (c < P_DIM) {
    int p = y * 82 + x;
    float4 v = *(const float4*)(W + p * 64 + kq);
    *(ushort4*)(Wp + c * 64 + kq) =
        make_ushort4(f2bf(v.x), f2bf(v.y), f2bf(v.z), f2bf(v.w));
    if (kq == 0) bp[c] = bias[p];
  } else {
    *(ushort4*)(Wp + c * 64 + kq) = make_ushort4(0, 0, 0, 0);
    if (kq == 0) bp[c] = 0.0f;
  }
}

// GEMM: out[m][n] = Abf[m][:] . Wp[n][:] + bp[n]
// grid (43, 64): 128x128 tile per block, 4 waves 2x2, 64x64 per wave.
// K=64 -> 2 MFMAs (16x16x32) per 16x16 acc tile, 32 MFMAs/wave.
__global__ __launch_bounds__(256) void gemm_kernel(
    const unsigned short* __restrict__ Abf,
    const unsigned short* __restrict__ Wp,
    const float* __restrict__ bp,
    float* __restrict__ out) {
  const int tid = threadIdx.x;
  const int wid = tid >> 6;
  const int lane = tid & 63;
  const int quad = lane >> 4;
  const int l16 = lane & 15;
  const int wm = (wid >> 1) * 64;   // wave row offset in 128-tile
  const int wn = (wid & 1) * 64;    // wave col offset
  const int m0 = blockIdx.y * 128 + wm;
  const int n0 = blockIdx.x * 128 + wn;

  // Fragment loads straight from global (L2-resident operands).
  // A-op layout: lane holds A[m = l16][k = quad*8 + j], j=0..7
  // B-op layout: lane holds B^T[n = l16][k = quad*8 + j]  (Wp is row-major [n][k])
  bf16x8 a_frag[4][2], b_frag[4][2];
#pragma unroll
  for (int i = 0; i < 4; ++i) {
#pragma unroll
    for (int kb = 0; kb < 2; ++kb) {
      a_frag[i][kb] = *(const bf16x8*)(Abf + (size_t)(m0 + i * 16 + l16) * 64 +
                                       kb * 32 + quad * 8);
      b_frag[i][kb] = *(const bf16x8*)(Wp + (size_t)(n0 + i * 16 + l16) * 64 +
                                       kb * 32 + quad * 8);
    }
  }

  f32x4 acc[4][4];
#pragma unroll
  for (int mi = 0; mi < 4; ++mi) {
#pragma unroll
    for (int ni = 0; ni < 4; ++ni) {
      f32x4 c = {0.0f, 0.0f, 0.0f, 0.0f};
      c = __builtin_amdgcn_mfma_f32_16x16x32_bf16(a_frag[mi][0], b_frag[ni][0], c, 0, 0, 0);
      c = __builtin_amdgcn_mfma_f32_16x16x32_bf16(a_frag[mi][1], b_frag[ni][1], c, 0, 0, 0);
      acc[mi][ni] = c;
    }
  }

  // Epilogue. C/D layout: col = l16, row = quad*4 + r.
  float biasv[4];
  int colv[4];
#pragma unroll
  for (int ni = 0; ni < 4; ++ni) {
    colv[ni] = n0 + ni * 16 + l16;
    biasv[ni] = (colv[ni] < P_DIM) ? bp[colv[ni]] : 0.0f;
  }
#pragma unroll
  for (int mi = 0; mi < 4; ++mi) {
#pragma unroll
    for (int r = 0; r < 4; ++r) {
      const int row = m0 + mi * 16 + quad * 4 + r;
      const size_t rb = (size_t)row * P_DIM;
#pragma unroll
      for (int ni = 0; ni < 4; ++ni) {  // ni innermost: 64 consecutive cols/wave
        if (colv[ni] < P_DIM) out[rb + colv[ni]] = acc[mi][ni][r] + biasv[ni];
      }
    }
  }
}

extern "C" void kernel_launch(void* const* d_in, const int* in_sizes, int n_in,
                              void* d_out, int out_size, void* d_ws, size_t ws_size,
                              hipStream_t stream) {
  (void)in_sizes; (void)n_in; (void)out_size; (void)ws_size;
  const float* A = (const float*)d_in[0];      // [8192, 64]
  const float* W = (const float*)d_in[1];      // [5494, 64]
  const float* bias = (const float*)d_in[2];   // [5494]
  float* out = (float*)d_out;                  // [8192, 82, 67, 1] contiguous

  // workspace layout (needs ~1.8 MB)
  unsigned short* Abf = (unsigned short*)d_ws;                       // 1 MB
  unsigned short* Wp = (unsigned short*)((char*)d_ws + 1048576);     // 704512 B
  float* bp = (float*)((char*)d_ws + 1048576 + 704512);              // 22016 B

  cvt_a_kernel<<<512, 256, 0, stream>>>(A, Abf);          // 8192*64/4/256
  cvt_w_kernel<<<344, 256, 0, stream>>>(W, bias, Wp, bp); // 5504*16/256
  gemm_kernel<<<dim3(PP_DIM / 128, B_DIM / 128), 256, 0, stream>>>(Abf, Wp, bp, out);
}